// Round 1
// baseline (878.573 us; speedup 1.0000x reference)
//
#include <hip/hip_runtime.h>
#include <math.h>

#define NEG_SLOPE 0.2f

// ---- ordered-uint encoding for float atomic max ----
__device__ __forceinline__ unsigned f2o(float f) {
  unsigned u = __float_as_uint(f);
  return (u & 0x80000000u) ? ~u : (u | 0x80000000u);
}
__device__ __forceinline__ float o2f(unsigned u) {
  return (u & 0x80000000u) ? __uint_as_float(u & 0x7fffffffu) : __uint_as_float(~u);
}

// ---- init: out1 = b1 (broadcast), out = b2 (broadcast), maxes/denoms zeroed ----
__global__ void init_k(float* __restrict__ out1, float* __restrict__ outF,
                       const float* __restrict__ b1, const float* __restrict__ b2,
                       unsigned* __restrict__ m1, float* __restrict__ d1,
                       unsigned* __restrict__ m2, float* __restrict__ d2, int N) {
  int stride = gridDim.x * blockDim.x;
  int i0 = blockIdx.x * blockDim.x + threadIdx.x;
  int t1 = N * 128;
  for (int i = i0; i < t1; i += stride) out1[i] = b1[i & 127];
  int t2 = N * 64;
  for (int i = i0; i < t2; i += stride) outF[i] = b2[i & 63];
  int t3 = N * 2;
  for (int i = i0; i < t3; i += stride) { m1[i] = 0u; d1[i] = 0.f; }
  for (int i = i0; i < N; i += stride) { m2[i] = 0u; d2[i] = 0.f; }
}

// ---- GEMM1: C[M,128] = A[M,256] @ B[256,128], f32 ----
__global__ __launch_bounds__(256) void gemm1_k(const float* __restrict__ A,
                                               const float* __restrict__ B,
                                               float* __restrict__ C, int M) {
  __shared__ float As[64][36];   // pad 36: 16B-aligned rows, bank-shifted
  __shared__ float Bs[32][128];
  const int tid = threadIdx.x;
  const int tx = tid & 15;
  const int ty = tid >> 4;
  const int row0 = blockIdx.x * 64;
  float acc[4][8];
#pragma unroll
  for (int i = 0; i < 4; ++i)
#pragma unroll
    for (int j = 0; j < 8; ++j) acc[i][j] = 0.f;

  const int ar = tid >> 3;        // 0..31
  const int ac = (tid & 7) * 4;   // 0..28
  const int br = tid >> 5;        // 0..7
  const int bc = (tid & 31) * 4;  // 0..124

  for (int k0 = 0; k0 < 256; k0 += 32) {
#pragma unroll
    for (int p = 0; p < 2; ++p) {
      int rr = ar + p * 32;
      int gr = row0 + rr; gr = gr < M ? gr : M - 1;
      float4 v = *reinterpret_cast<const float4*>(&A[(size_t)gr * 256 + k0 + ac]);
      As[rr][ac] = v.x; As[rr][ac + 1] = v.y; As[rr][ac + 2] = v.z; As[rr][ac + 3] = v.w;
    }
#pragma unroll
    for (int p = 0; p < 4; ++p) {
      int rr = br + p * 8;
      float4 v = *reinterpret_cast<const float4*>(&B[(size_t)(k0 + rr) * 128 + bc]);
      *reinterpret_cast<float4*>(&Bs[rr][bc]) = v;
    }
    __syncthreads();
#pragma unroll
    for (int kk = 0; kk < 32; ++kk) {
      float aa[4];
#pragma unroll
      for (int i = 0; i < 4; ++i) aa[i] = As[ty * 4 + i][kk];
      float4 b0 = *reinterpret_cast<const float4*>(&Bs[kk][tx * 4]);
      float4 b1 = *reinterpret_cast<const float4*>(&Bs[kk][64 + tx * 4]);
      float bb[8] = {b0.x, b0.y, b0.z, b0.w, b1.x, b1.y, b1.z, b1.w};
#pragma unroll
      for (int i = 0; i < 4; ++i)
#pragma unroll
        for (int j = 0; j < 8; ++j) acc[i][j] = fmaf(aa[i], bb[j], acc[i][j]);
    }
    __syncthreads();
  }
#pragma unroll
  for (int i = 0; i < 4; ++i) {
    int gr = row0 + ty * 4 + i;
    if (gr < M) {
      float4 v0 = make_float4(acc[i][0], acc[i][1], acc[i][2], acc[i][3]);
      float4 v1 = make_float4(acc[i][4], acc[i][5], acc[i][6], acc[i][7]);
      *reinterpret_cast<float4*>(&C[(size_t)gr * 128 + tx * 4]) = v0;
      *reinterpret_cast<float4*>(&C[(size_t)gr * 128 + 64 + tx * 4]) = v1;
    }
  }
}

// ---- GEMM2: C[M,64] = relu(A[M,128]) @ B[128,64]  (bias already in A) ----
__global__ __launch_bounds__(256) void gemm2_k(const float* __restrict__ A,
                                               const float* __restrict__ B,
                                               float* __restrict__ C, int M) {
  __shared__ float As[64][36];
  __shared__ float Bs[32][64];
  const int tid = threadIdx.x;
  const int tx = tid & 15;
  const int ty = tid >> 4;
  const int row0 = blockIdx.x * 64;
  float acc[4][4];
#pragma unroll
  for (int i = 0; i < 4; ++i)
#pragma unroll
    for (int j = 0; j < 4; ++j) acc[i][j] = 0.f;

  const int ar = tid >> 3;        // 0..31
  const int ac = (tid & 7) * 4;   // 0..28
  const int br = tid >> 4;        // 0..15
  const int bc = (tid & 15) * 4;  // 0..60

  for (int k0 = 0; k0 < 128; k0 += 32) {
#pragma unroll
    for (int p = 0; p < 2; ++p) {
      int rr = ar + p * 32;
      int gr = row0 + rr; gr = gr < M ? gr : M - 1;
      float4 v = *reinterpret_cast<const float4*>(&A[(size_t)gr * 128 + k0 + ac]);
      As[rr][ac]     = fmaxf(v.x, 0.f);
      As[rr][ac + 1] = fmaxf(v.y, 0.f);
      As[rr][ac + 2] = fmaxf(v.z, 0.f);
      As[rr][ac + 3] = fmaxf(v.w, 0.f);
    }
#pragma unroll
    for (int p = 0; p < 2; ++p) {
      int rr = br + p * 16;
      float4 v = *reinterpret_cast<const float4*>(&B[(size_t)(k0 + rr) * 64 + bc]);
      *reinterpret_cast<float4*>(&Bs[rr][bc]) = v;
    }
    __syncthreads();
#pragma unroll
    for (int kk = 0; kk < 32; ++kk) {
      float aa[4];
#pragma unroll
      for (int i = 0; i < 4; ++i) aa[i] = As[ty * 4 + i][kk];
      float4 b = *reinterpret_cast<const float4*>(&Bs[kk][tx * 4]);
      float bb[4] = {b.x, b.y, b.z, b.w};
#pragma unroll
      for (int i = 0; i < 4; ++i)
#pragma unroll
        for (int j = 0; j < 4; ++j) acc[i][j] = fmaf(aa[i], bb[j], acc[i][j]);
    }
    __syncthreads();
  }
#pragma unroll
  for (int i = 0; i < 4; ++i) {
    int gr = row0 + ty * 4 + i;
    if (gr < M) {
      float4 v = make_float4(acc[i][0], acc[i][1], acc[i][2], acc[i][3]);
      *reinterpret_cast<float4*>(&C[(size_t)gr * 64 + tx * 4]) = v;
    }
  }
}

// ---- per-node attention scores, layer 1 (2 heads x 64 dims): wave per node ----
__global__ __launch_bounds__(256) void att1_k(const float* __restrict__ h1,
                                              const float* __restrict__ asv,
                                              const float* __restrict__ adv,
                                              float* __restrict__ aS, float* __restrict__ aD,
                                              int N) {
  int w = (blockIdx.x * 256 + threadIdx.x) >> 6;
  int lane = threadIdx.x & 63;
  if (w >= N) return;
  float v0 = h1[(size_t)w * 128 + lane];
  float v1 = h1[(size_t)w * 128 + 64 + lane];
  float s0 = v0 * asv[lane], s1 = v1 * asv[64 + lane];
  float d0 = v0 * adv[lane], d1 = v1 * adv[64 + lane];
#pragma unroll
  for (int off = 32; off > 0; off >>= 1) {
    s0 += __shfl_xor(s0, off);
    s1 += __shfl_xor(s1, off);
    d0 += __shfl_xor(d0, off);
    d1 += __shfl_xor(d1, off);
  }
  if (lane == 0) {
    aS[w * 2] = s0; aS[w * 2 + 1] = s1;
    aD[w * 2] = d0; aD[w * 2 + 1] = d1;
  }
}

// ---- per-node attention scores, layer 2 (1 head x 64): wave per node ----
__global__ __launch_bounds__(256) void att2_k(const float* __restrict__ h2,
                                              const float* __restrict__ asv,
                                              const float* __restrict__ adv,
                                              float* __restrict__ aS, float* __restrict__ aD,
                                              int N) {
  int w = (blockIdx.x * 256 + threadIdx.x) >> 6;
  int lane = threadIdx.x & 63;
  if (w >= N) return;
  float v = h2[(size_t)w * 64 + lane];
  float s = v * asv[lane];
  float d = v * adv[lane];
#pragma unroll
  for (int off = 32; off > 0; off >>= 1) {
    s += __shfl_xor(s, off);
    d += __shfl_xor(d, off);
  }
  if (lane == 0) { aS[w] = s; aD[w] = d; }
}

// ---- edge max, layer 1 (2 heads) ----
__global__ void edge_max1_k(const int* __restrict__ ei, const float* __restrict__ aS,
                            const float* __restrict__ aD, unsigned* __restrict__ m1,
                            int E, int NE) {
  int e = blockIdx.x * blockDim.x + threadIdx.x;
  if (e >= NE) return;
  int src, dst;
  if (e < E) { src = ei[e]; dst = ei[E + e]; } else { src = e - E; dst = src; }
#pragma unroll
  for (int h = 0; h < 2; ++h) {
    float s = aS[src * 2 + h] + aD[dst * 2 + h];
    s = s > 0.f ? s : NEG_SLOPE * s;
    atomicMax(&m1[dst * 2 + h], f2o(s));
  }
}

// ---- edge exp-sum, layer 1 ----
__global__ void edge_sum1_k(const int* __restrict__ ei, const float* __restrict__ aS,
                            const float* __restrict__ aD, const unsigned* __restrict__ m1,
                            float* __restrict__ d1, int E, int NE) {
  int e = blockIdx.x * blockDim.x + threadIdx.x;
  if (e >= NE) return;
  int src, dst;
  if (e < E) { src = ei[e]; dst = ei[E + e]; } else { src = e - E; dst = src; }
#pragma unroll
  for (int h = 0; h < 2; ++h) {
    float s = aS[src * 2 + h] + aD[dst * 2 + h];
    s = s > 0.f ? s : NEG_SLOPE * s;
    atomicAdd(&d1[dst * 2 + h], __expf(s - o2f(m1[dst * 2 + h])));
  }
}

// ---- aggregation, layer 1: wave per edge, 128 features ----
__global__ __launch_bounds__(256) void agg1_k(const int* __restrict__ ei,
                                              const float* __restrict__ aS,
                                              const float* __restrict__ aD,
                                              const unsigned* __restrict__ m1,
                                              const float* __restrict__ d1,
                                              const float* __restrict__ h1,
                                              float* __restrict__ out1, int E, int NE) {
  int w = (blockIdx.x * 256 + threadIdx.x) >> 6;
  if (w >= NE) return;
  int lane = threadIdx.x & 63;
  int src, dst;
  if (w < E) { src = ei[w]; dst = ei[E + w]; } else { src = w - E; dst = src; }
  float s = aS[src * 2] + aD[dst * 2];
  s = s > 0.f ? s : NEG_SLOPE * s;
  float al0 = __expf(s - o2f(m1[dst * 2])) / d1[dst * 2];
  float t = aS[src * 2 + 1] + aD[dst * 2 + 1];
  t = t > 0.f ? t : NEG_SLOPE * t;
  float al1 = __expf(t - o2f(m1[dst * 2 + 1])) / d1[dst * 2 + 1];
  atomicAdd(&out1[(size_t)dst * 128 + lane], al0 * h1[(size_t)src * 128 + lane]);
  atomicAdd(&out1[(size_t)dst * 128 + 64 + lane], al1 * h1[(size_t)src * 128 + 64 + lane]);
}

// ---- edge max, layer 2 (1 head) ----
__global__ void edge_max2_k(const int* __restrict__ ei, const float* __restrict__ aS,
                            const float* __restrict__ aD, unsigned* __restrict__ m2,
                            int E, int NE) {
  int e = blockIdx.x * blockDim.x + threadIdx.x;
  if (e >= NE) return;
  int src, dst;
  if (e < E) { src = ei[e]; dst = ei[E + e]; } else { src = e - E; dst = src; }
  float s = aS[src] + aD[dst];
  s = s > 0.f ? s : NEG_SLOPE * s;
  atomicMax(&m2[dst], f2o(s));
}

// ---- edge exp-sum, layer 2 ----
__global__ void edge_sum2_k(const int* __restrict__ ei, const float* __restrict__ aS,
                            const float* __restrict__ aD, const unsigned* __restrict__ m2,
                            float* __restrict__ d2, int E, int NE) {
  int e = blockIdx.x * blockDim.x + threadIdx.x;
  if (e >= NE) return;
  int src, dst;
  if (e < E) { src = ei[e]; dst = ei[E + e]; } else { src = e - E; dst = src; }
  float s = aS[src] + aD[dst];
  s = s > 0.f ? s : NEG_SLOPE * s;
  atomicAdd(&d2[dst], __expf(s - o2f(m2[dst])));
}

// ---- aggregation, layer 2: wave per edge, 64 features, writes final out ----
__global__ __launch_bounds__(256) void agg2_k(const int* __restrict__ ei,
                                              const float* __restrict__ aS,
                                              const float* __restrict__ aD,
                                              const unsigned* __restrict__ m2,
                                              const float* __restrict__ d2,
                                              const float* __restrict__ h2,
                                              float* __restrict__ out, int E, int NE) {
  int w = (blockIdx.x * 256 + threadIdx.x) >> 6;
  if (w >= NE) return;
  int lane = threadIdx.x & 63;
  int src, dst;
  if (w < E) { src = ei[w]; dst = ei[E + w]; } else { src = w - E; dst = src; }
  float s = aS[src] + aD[dst];
  s = s > 0.f ? s : NEG_SLOPE * s;
  float al = __expf(s - o2f(m2[dst])) / d2[dst];
  atomicAdd(&out[(size_t)dst * 64 + lane], al * h2[(size_t)src * 64 + lane]);
}

extern "C" void kernel_launch(void* const* d_in, const int* in_sizes, int n_in,
                              void* d_out, int out_size, void* d_ws, size_t ws_size,
                              hipStream_t stream) {
  const float* x   = (const float*)d_in[0];
  const int*   ei  = (const int*)d_in[1];
  const float* W1  = (const float*)d_in[2];
  const float* as1 = (const float*)d_in[3];
  const float* ad1 = (const float*)d_in[4];
  const float* b1  = (const float*)d_in[5];
  const float* W2  = (const float*)d_in[6];
  const float* as2 = (const float*)d_in[7];
  const float* ad2 = (const float*)d_in[8];
  const float* b2  = (const float*)d_in[9];
  float* out = (float*)d_out;

  const int N = in_sizes[0] / 256;
  const int E = in_sizes[1] / 2;
  const int NE = E + N;

  char* ws = (char*)d_ws;
  size_t off = 0;
  auto take = [&](size_t bytes) -> char* {
    char* p = ws + off;
    off += (bytes + 255) & ~(size_t)255;
    return p;
  };
  float*    h1  = (float*)take((size_t)N * 128 * 4);  // reused as h2 after agg1
  float*    out1 = (float*)take((size_t)N * 128 * 4);
  float*    aS1 = (float*)take((size_t)N * 2 * 4);
  float*    aD1 = (float*)take((size_t)N * 2 * 4);
  unsigned* m1  = (unsigned*)take((size_t)N * 2 * 4);
  float*    d1  = (float*)take((size_t)N * 2 * 4);
  float*    aS2 = (float*)take((size_t)N * 4);
  float*    aD2 = (float*)take((size_t)N * 4);
  unsigned* m2  = (unsigned*)take((size_t)N * 4);
  float*    d2  = (float*)take((size_t)N * 4);
  float*    h2  = h1;  // alias: h1 dead after agg1_k

  const int eb = 256;
  const int egrid = (NE + eb - 1) / eb;
  const int wgrid = (NE + 3) / 4;          // wave-per-edge kernels, 4 waves/block
  const int ngrid = (N * 64 + 255) / 256;  // wave-per-node kernels
  const int ggrid = (N + 63) / 64;

  init_k<<<2048, 256, 0, stream>>>(out1, out, b1, b2, m1, d1, m2, d2, N);
  gemm1_k<<<ggrid, 256, 0, stream>>>(x, W1, h1, N);
  att1_k<<<ngrid, 256, 0, stream>>>(h1, as1, ad1, aS1, aD1, N);
  edge_max1_k<<<egrid, eb, 0, stream>>>(ei, aS1, aD1, m1, E, NE);
  edge_sum1_k<<<egrid, eb, 0, stream>>>(ei, aS1, aD1, m1, d1, E, NE);
  agg1_k<<<wgrid, 256, 0, stream>>>(ei, aS1, aD1, m1, d1, h1, out1, E, NE);
  gemm2_k<<<ggrid, 256, 0, stream>>>(out1, W2, h2, N);
  att2_k<<<ngrid, 256, 0, stream>>>(h2, as2, ad2, aS2, aD2, N);
  edge_max2_k<<<egrid, eb, 0, stream>>>(ei, aS2, aD2, m2, E, NE);
  edge_sum2_k<<<egrid, eb, 0, stream>>>(ei, aS2, aD2, m2, d2, E, NE);
  agg2_k<<<wgrid, 256, 0, stream>>>(ei, aS2, aD2, m2, d2, h2, out, E, NE);
}

// Round 2
// 441.681 us; speedup vs baseline: 1.9892x; 1.9892x over previous
//
#include <hip/hip_runtime.h>
#include <math.h>

#define NEG_SLOPE 0.2f

// ================= CSR build =================
// rank[e] = arrival order of edge e at its dst; deg[d] = in-degree of d.
__global__ void hist_k(const int* __restrict__ ei, int* __restrict__ deg,
                       int* __restrict__ rank, int E, int NE) {
  int e = blockIdx.x * blockDim.x + threadIdx.x;
  if (e >= NE) return;
  int dst = (e < E) ? ei[E + e] : e - E;
  rank[e] = atomicAdd(&deg[dst], 1);
}

// Per-block exclusive scan of deg -> part; block totals -> bsum.
__global__ void scan1_k(const int* __restrict__ deg, int* __restrict__ part,
                        int* __restrict__ bsum, int N) {
  __shared__ int tmp[256];
  int i = blockIdx.x * 256 + threadIdx.x;
  int v = (i < N) ? deg[i] : 0;
  tmp[threadIdx.x] = v;
  __syncthreads();
#pragma unroll
  for (int off = 1; off < 256; off <<= 1) {
    int t = (threadIdx.x >= off) ? tmp[threadIdx.x - off] : 0;
    __syncthreads();
    tmp[threadIdx.x] += t;
    __syncthreads();
  }
  if (i < N) part[i] = tmp[threadIdx.x] - v;  // exclusive within block
  if (threadIdx.x == 255) bsum[blockIdx.x] = tmp[255];
}

// Single-block exclusive scan of block sums (nb <= 256).
__global__ void scan2_k(int* __restrict__ bsum, int nb) {
  __shared__ int tmp[256];
  int v = (threadIdx.x < nb) ? bsum[threadIdx.x] : 0;
  tmp[threadIdx.x] = v;
  __syncthreads();
#pragma unroll
  for (int off = 1; off < 256; off <<= 1) {
    int t = (threadIdx.x >= off) ? tmp[threadIdx.x - off] : 0;
    __syncthreads();
    tmp[threadIdx.x] += t;
    __syncthreads();
  }
  if (threadIdx.x < nb) bsum[threadIdx.x] = tmp[threadIdx.x] - v;
}

__global__ void scan3_k(const int* __restrict__ part, const int* __restrict__ bsum,
                        int* __restrict__ off, int N, int NE) {
  int i = blockIdx.x * 256 + threadIdx.x;
  if (i < N) off[i] = part[i] + bsum[blockIdx.x];
  if (i == 0) off[N] = NE;
}

__global__ void scatter_k(const int* __restrict__ ei, const int* __restrict__ off,
                          const int* __restrict__ rank, int* __restrict__ eidx,
                          int E, int NE) {
  int e = blockIdx.x * blockDim.x + threadIdx.x;
  if (e >= NE) return;
  int dst = (e < E) ? ei[E + e] : e - E;
  eidx[off[dst] + rank[e]] = e;
}

// ================= GEMMs (f32 vector) =================
__global__ __launch_bounds__(256) void gemm1_k(const float* __restrict__ A,
                                               const float* __restrict__ B,
                                               float* __restrict__ C, int M) {
  __shared__ float As[64][36];
  __shared__ float Bs[32][128];
  const int tid = threadIdx.x;
  const int tx = tid & 15;
  const int ty = tid >> 4;
  const int row0 = blockIdx.x * 64;
  float acc[4][8];
#pragma unroll
  for (int i = 0; i < 4; ++i)
#pragma unroll
    for (int j = 0; j < 8; ++j) acc[i][j] = 0.f;

  const int ar = tid >> 3;
  const int ac = (tid & 7) * 4;
  const int br = tid >> 5;
  const int bc = (tid & 31) * 4;

  for (int k0 = 0; k0 < 256; k0 += 32) {
#pragma unroll
    for (int p = 0; p < 2; ++p) {
      int rr = ar + p * 32;
      int gr = row0 + rr; gr = gr < M ? gr : M - 1;
      float4 v = *reinterpret_cast<const float4*>(&A[(size_t)gr * 256 + k0 + ac]);
      As[rr][ac] = v.x; As[rr][ac + 1] = v.y; As[rr][ac + 2] = v.z; As[rr][ac + 3] = v.w;
    }
#pragma unroll
    for (int p = 0; p < 4; ++p) {
      int rr = br + p * 8;
      float4 v = *reinterpret_cast<const float4*>(&B[(size_t)(k0 + rr) * 128 + bc]);
      *reinterpret_cast<float4*>(&Bs[rr][bc]) = v;
    }
    __syncthreads();
#pragma unroll
    for (int kk = 0; kk < 32; ++kk) {
      float aa[4];
#pragma unroll
      for (int i = 0; i < 4; ++i) aa[i] = As[ty * 4 + i][kk];
      float4 b0 = *reinterpret_cast<const float4*>(&Bs[kk][tx * 4]);
      float4 b1 = *reinterpret_cast<const float4*>(&Bs[kk][64 + tx * 4]);
      float bb[8] = {b0.x, b0.y, b0.z, b0.w, b1.x, b1.y, b1.z, b1.w};
#pragma unroll
      for (int i = 0; i < 4; ++i)
#pragma unroll
        for (int j = 0; j < 8; ++j) acc[i][j] = fmaf(aa[i], bb[j], acc[i][j]);
    }
    __syncthreads();
  }
#pragma unroll
  for (int i = 0; i < 4; ++i) {
    int gr = row0 + ty * 4 + i;
    if (gr < M) {
      float4 v0 = make_float4(acc[i][0], acc[i][1], acc[i][2], acc[i][3]);
      float4 v1 = make_float4(acc[i][4], acc[i][5], acc[i][6], acc[i][7]);
      *reinterpret_cast<float4*>(&C[(size_t)gr * 128 + tx * 4]) = v0;
      *reinterpret_cast<float4*>(&C[(size_t)gr * 128 + 64 + tx * 4]) = v1;
    }
  }
}

__global__ __launch_bounds__(256) void gemm2_k(const float* __restrict__ A,
                                               const float* __restrict__ B,
                                               float* __restrict__ C, int M) {
  __shared__ float As[64][36];
  __shared__ float Bs[32][64];
  const int tid = threadIdx.x;
  const int tx = tid & 15;
  const int ty = tid >> 4;
  const int row0 = blockIdx.x * 64;
  float acc[4][4];
#pragma unroll
  for (int i = 0; i < 4; ++i)
#pragma unroll
    for (int j = 0; j < 4; ++j) acc[i][j] = 0.f;

  const int ar = tid >> 3;
  const int ac = (tid & 7) * 4;
  const int br = tid >> 4;
  const int bc = (tid & 15) * 4;

  for (int k0 = 0; k0 < 128; k0 += 32) {
#pragma unroll
    for (int p = 0; p < 2; ++p) {
      int rr = ar + p * 32;
      int gr = row0 + rr; gr = gr < M ? gr : M - 1;
      float4 v = *reinterpret_cast<const float4*>(&A[(size_t)gr * 128 + k0 + ac]);
      As[rr][ac]     = fmaxf(v.x, 0.f);
      As[rr][ac + 1] = fmaxf(v.y, 0.f);
      As[rr][ac + 2] = fmaxf(v.z, 0.f);
      As[rr][ac + 3] = fmaxf(v.w, 0.f);
    }
#pragma unroll
    for (int p = 0; p < 2; ++p) {
      int rr = br + p * 16;
      float4 v = *reinterpret_cast<const float4*>(&B[(size_t)(k0 + rr) * 64 + bc]);
      *reinterpret_cast<float4*>(&Bs[rr][bc]) = v;
    }
    __syncthreads();
#pragma unroll
    for (int kk = 0; kk < 32; ++kk) {
      float aa[4];
#pragma unroll
      for (int i = 0; i < 4; ++i) aa[i] = As[ty * 4 + i][kk];
      float4 b = *reinterpret_cast<const float4*>(&Bs[kk][tx * 4]);
      float bb[4] = {b.x, b.y, b.z, b.w};
#pragma unroll
      for (int i = 0; i < 4; ++i)
#pragma unroll
        for (int j = 0; j < 4; ++j) acc[i][j] = fmaf(aa[i], bb[j], acc[i][j]);
    }
    __syncthreads();
  }
#pragma unroll
  for (int i = 0; i < 4; ++i) {
    int gr = row0 + ty * 4 + i;
    if (gr < M) {
      float4 v = make_float4(acc[i][0], acc[i][1], acc[i][2], acc[i][3]);
      *reinterpret_cast<float4*>(&C[(size_t)gr * 64 + tx * 4]) = v;
    }
  }
}

// ================= per-node attention scores =================
__global__ __launch_bounds__(256) void att1_k(const float* __restrict__ h1,
                                              const float* __restrict__ asv,
                                              const float* __restrict__ adv,
                                              float* __restrict__ aS, float* __restrict__ aD,
                                              int N) {
  int w = (blockIdx.x * 256 + threadIdx.x) >> 6;
  int lane = threadIdx.x & 63;
  if (w >= N) return;
  float v0 = h1[(size_t)w * 128 + lane];
  float v1 = h1[(size_t)w * 128 + 64 + lane];
  float s0 = v0 * asv[lane], s1 = v1 * asv[64 + lane];
  float d0 = v0 * adv[lane], d1 = v1 * adv[64 + lane];
#pragma unroll
  for (int off = 32; off > 0; off >>= 1) {
    s0 += __shfl_xor(s0, off);
    s1 += __shfl_xor(s1, off);
    d0 += __shfl_xor(d0, off);
    d1 += __shfl_xor(d1, off);
  }
  if (lane == 0) {
    aS[w * 2] = s0; aS[w * 2 + 1] = s1;
    aD[w * 2] = d0; aD[w * 2 + 1] = d1;
  }
}

__global__ __launch_bounds__(256) void att2_k(const float* __restrict__ h2,
                                              const float* __restrict__ asv,
                                              const float* __restrict__ adv,
                                              float* __restrict__ aS, float* __restrict__ aD,
                                              int N) {
  int w = (blockIdx.x * 256 + threadIdx.x) >> 6;
  int lane = threadIdx.x & 63;
  if (w >= N) return;
  float v = h2[(size_t)w * 64 + lane];
  float s = v * asv[lane];
  float d = v * adv[lane];
#pragma unroll
  for (int off = 32; off > 0; off >>= 1) {
    s += __shfl_xor(s, off);
    d += __shfl_xor(d, off);
  }
  if (lane == 0) { aS[w] = s; aD[w] = d; }
}

// ================= CSR aggregation: fused max/sum/gather, wave per dst =================
__global__ __launch_bounds__(256) void csr_agg1_k(const int* __restrict__ ei,
                                                  const int* __restrict__ off,
                                                  const int* __restrict__ eidx,
                                                  const float* __restrict__ aS,
                                                  const float* __restrict__ aD,
                                                  const float* __restrict__ h1,
                                                  const float* __restrict__ b1,
                                                  float* __restrict__ out1, int N, int E) {
  int d = (blockIdx.x * 256 + threadIdx.x) >> 6;
  if (d >= N) return;
  int lane = threadIdx.x & 63;
  int s0 = off[d], s1 = off[d + 1];
  float aD0 = aD[d * 2], aD1 = aD[d * 2 + 1];

  // pass A: per-head max over this node's incoming edges
  float m0 = -1e30f, m1 = -1e30f;
  for (int i = s0 + lane; i < s1; i += 64) {
    int e = eidx[i];
    int src = (e < E) ? ei[e] : e - E;
    float2 sv = *reinterpret_cast<const float2*>(&aS[src * 2]);
    float t0 = sv.x + aD0; t0 = t0 > 0.f ? t0 : NEG_SLOPE * t0;
    float t1 = sv.y + aD1; t1 = t1 > 0.f ? t1 : NEG_SLOPE * t1;
    m0 = fmaxf(m0, t0); m1 = fmaxf(m1, t1);
  }
#pragma unroll
  for (int o = 32; o > 0; o >>= 1) {
    m0 = fmaxf(m0, __shfl_xor(m0, o));
    m1 = fmaxf(m1, __shfl_xor(m1, o));
  }
  // pass B: exp-sum
  float sum0 = 0.f, sum1 = 0.f;
  for (int i = s0 + lane; i < s1; i += 64) {
    int e = eidx[i];
    int src = (e < E) ? ei[e] : e - E;
    float2 sv = *reinterpret_cast<const float2*>(&aS[src * 2]);
    float t0 = sv.x + aD0; t0 = t0 > 0.f ? t0 : NEG_SLOPE * t0;
    float t1 = sv.y + aD1; t1 = t1 > 0.f ? t1 : NEG_SLOPE * t1;
    sum0 += __expf(t0 - m0); sum1 += __expf(t1 - m1);
  }
#pragma unroll
  for (int o = 32; o > 0; o >>= 1) {
    sum0 += __shfl_xor(sum0, o);
    sum1 += __shfl_xor(sum1, o);
  }
  float inv0 = 1.f / sum0, inv1 = 1.f / sum1;

  // pass C: gather + accumulate (bias folded into init)
  float acc0 = b1[lane], acc1 = b1[64 + lane];
  for (int i = s0; i < s1; ++i) {
    int e = eidx[i];
    int src = (e < E) ? ei[e] : e - E;
    float2 sv = *reinterpret_cast<const float2*>(&aS[src * 2]);
    float t0 = sv.x + aD0; t0 = t0 > 0.f ? t0 : NEG_SLOPE * t0;
    float t1 = sv.y + aD1; t1 = t1 > 0.f ? t1 : NEG_SLOPE * t1;
    float a0 = __expf(t0 - m0) * inv0;
    float a1 = __expf(t1 - m1) * inv1;
    acc0 = fmaf(a0, h1[(size_t)src * 128 + lane], acc0);
    acc1 = fmaf(a1, h1[(size_t)src * 128 + 64 + lane], acc1);
  }
  out1[(size_t)d * 128 + lane] = acc0;
  out1[(size_t)d * 128 + 64 + lane] = acc1;
}

__global__ __launch_bounds__(256) void csr_agg2_k(const int* __restrict__ ei,
                                                  const int* __restrict__ off,
                                                  const int* __restrict__ eidx,
                                                  const float* __restrict__ aS,
                                                  const float* __restrict__ aD,
                                                  const float* __restrict__ h2,
                                                  const float* __restrict__ b2,
                                                  float* __restrict__ out, int N, int E) {
  int d = (blockIdx.x * 256 + threadIdx.x) >> 6;
  if (d >= N) return;
  int lane = threadIdx.x & 63;
  int s0 = off[d], s1 = off[d + 1];
  float aDd = aD[d];

  float m = -1e30f;
  for (int i = s0 + lane; i < s1; i += 64) {
    int e = eidx[i];
    int src = (e < E) ? ei[e] : e - E;
    float t = aS[src] + aDd; t = t > 0.f ? t : NEG_SLOPE * t;
    m = fmaxf(m, t);
  }
#pragma unroll
  for (int o = 32; o > 0; o >>= 1) m = fmaxf(m, __shfl_xor(m, o));

  float sum = 0.f;
  for (int i = s0 + lane; i < s1; i += 64) {
    int e = eidx[i];
    int src = (e < E) ? ei[e] : e - E;
    float t = aS[src] + aDd; t = t > 0.f ? t : NEG_SLOPE * t;
    sum += __expf(t - m);
  }
#pragma unroll
  for (int o = 32; o > 0; o >>= 1) sum += __shfl_xor(sum, o);
  float inv = 1.f / sum;

  float acc = b2[lane];
  for (int i = s0; i < s1; ++i) {
    int e = eidx[i];
    int src = (e < E) ? ei[e] : e - E;
    float t = aS[src] + aDd; t = t > 0.f ? t : NEG_SLOPE * t;
    float a = __expf(t - m) * inv;
    acc = fmaf(a, h2[(size_t)src * 64 + lane], acc);
  }
  out[(size_t)d * 64 + lane] = acc;
}

extern "C" void kernel_launch(void* const* d_in, const int* in_sizes, int n_in,
                              void* d_out, int out_size, void* d_ws, size_t ws_size,
                              hipStream_t stream) {
  const float* x   = (const float*)d_in[0];
  const int*   ei  = (const int*)d_in[1];
  const float* W1  = (const float*)d_in[2];
  const float* as1 = (const float*)d_in[3];
  const float* ad1 = (const float*)d_in[4];
  const float* b1  = (const float*)d_in[5];
  const float* W2  = (const float*)d_in[6];
  const float* as2 = (const float*)d_in[7];
  const float* ad2 = (const float*)d_in[8];
  const float* b2  = (const float*)d_in[9];
  float* out = (float*)d_out;

  const int N = in_sizes[0] / 256;
  const int E = in_sizes[1] / 2;
  const int NE = E + N;

  char* ws = (char*)d_ws;
  size_t woff = 0;
  auto take = [&](size_t bytes) -> char* {
    char* p = ws + woff;
    woff += (bytes + 255) & ~(size_t)255;
    return p;
  };
  float* h1   = (float*)take((size_t)N * 128 * 4);   // reused as h2
  float* out1 = (float*)take((size_t)N * 128 * 4);
  float* aS1  = (float*)take((size_t)N * 2 * 4);
  float* aD1  = (float*)take((size_t)N * 2 * 4);
  float* aS2  = (float*)take((size_t)N * 4);
  float* aD2  = (float*)take((size_t)N * 4);
  int*   deg  = (int*)take((size_t)N * 4);
  int*   part = (int*)take((size_t)N * 4);
  int*   offs = (int*)take((size_t)(N + 1) * 4);
  int*   bsum = (int*)take(256 * 4);
  int*   rank = (int*)take((size_t)NE * 4);
  int*   eidx = (int*)take((size_t)NE * 4);
  float* h2   = h1;

  const int egrid = (NE + 255) / 256;
  const int wgrid = (N + 3) / 4;           // wave-per-node
  const int ngrid = (N * 64 + 255) / 256;
  const int ggrid = (N + 63) / 64;
  const int nb    = (N + 255) / 256;       // scan blocks (<=256 required)

  // ---- CSR build (shared by both layers) ----
  hipMemsetAsync(deg, 0, (size_t)N * 4, stream);
  hist_k<<<egrid, 256, 0, stream>>>(ei, deg, rank, E, NE);
  scan1_k<<<nb, 256, 0, stream>>>(deg, part, bsum, N);
  scan2_k<<<1, 256, 0, stream>>>(bsum, nb);
  scan3_k<<<nb, 256, 0, stream>>>(part, bsum, offs, N, NE);
  scatter_k<<<egrid, 256, 0, stream>>>(ei, offs, rank, eidx, E, NE);

  // ---- layer 1 ----
  gemm1_k<<<ggrid, 256, 0, stream>>>(x, W1, h1, N);
  att1_k<<<ngrid, 256, 0, stream>>>(h1, as1, ad1, aS1, aD1, N);
  csr_agg1_k<<<wgrid, 256, 0, stream>>>(ei, offs, eidx, aS1, aD1, h1, b1, out1, N, E);

  // ---- layer 2 ----
  gemm2_k<<<ggrid, 256, 0, stream>>>(out1, W2, h2, N);
  att2_k<<<ngrid, 256, 0, stream>>>(h2, as2, ad2, aS2, aD2, N);
  csr_agg2_k<<<wgrid, 256, 0, stream>>>(ei, offs, eidx, aS2, aD2, h2, b2, out, N, E);
}

// Round 3
// 261.513 us; speedup vs baseline: 3.3596x; 1.6889x over previous
//
#include <hip/hip_runtime.h>
#include <math.h>

#define NEG_SLOPE 0.2f

__device__ __forceinline__ float lrelu(float x) { return x > 0.f ? x : NEG_SLOPE * x; }

// ================= CSR build =================
__global__ void hist_k(const int* __restrict__ ei, int* __restrict__ deg,
                       int* __restrict__ rank, int E, int NE) {
  int e = blockIdx.x * blockDim.x + threadIdx.x;
  if (e >= NE) return;
  int dst = (e < E) ? ei[E + e] : e - E;
  rank[e] = atomicAdd(&deg[dst], 1);
}

__global__ void scan1_k(const int* __restrict__ deg, int* __restrict__ part,
                        int* __restrict__ bsum, int N) {
  __shared__ int tmp[256];
  int i = blockIdx.x * 256 + threadIdx.x;
  int v = (i < N) ? deg[i] : 0;
  tmp[threadIdx.x] = v;
  __syncthreads();
#pragma unroll
  for (int off = 1; off < 256; off <<= 1) {
    int t = (threadIdx.x >= off) ? tmp[threadIdx.x - off] : 0;
    __syncthreads();
    tmp[threadIdx.x] += t;
    __syncthreads();
  }
  if (i < N) part[i] = tmp[threadIdx.x] - v;
  if (threadIdx.x == 255) bsum[blockIdx.x] = tmp[255];
}

__global__ void scan2_k(int* __restrict__ bsum, int nb) {
  __shared__ int tmp[256];
  int v = (threadIdx.x < nb) ? bsum[threadIdx.x] : 0;
  tmp[threadIdx.x] = v;
  __syncthreads();
#pragma unroll
  for (int off = 1; off < 256; off <<= 1) {
    int t = (threadIdx.x >= off) ? tmp[threadIdx.x - off] : 0;
    __syncthreads();
    tmp[threadIdx.x] += t;
    __syncthreads();
  }
  if (threadIdx.x < nb) bsum[threadIdx.x] = tmp[threadIdx.x] - v;
}

__global__ void scan3_k(const int* __restrict__ part, const int* __restrict__ bsum,
                        int* __restrict__ off, int N, int NE) {
  int i = blockIdx.x * 256 + threadIdx.x;
  if (i < N) off[i] = part[i] + bsum[blockIdx.x];
  if (i == 0) off[N] = NE;
}

// stores SRC node id directly (kills one indirection in the agg kernels)
__global__ void scatter_k(const int* __restrict__ ei, const int* __restrict__ off,
                          const int* __restrict__ rank, int* __restrict__ srcs,
                          int E, int NE) {
  int e = blockIdx.x * blockDim.x + threadIdx.x;
  if (e >= NE) return;
  int src, dst;
  if (e < E) { src = ei[e]; dst = ei[E + e]; } else { src = e - E; dst = src; }
  srcs[off[dst] + rank[e]] = src;
}

// ================= GEMMs (f32 vector) =================
__global__ __launch_bounds__(256) void gemm1_k(const float* __restrict__ A,
                                               const float* __restrict__ B,
                                               float* __restrict__ C, int M) {
  __shared__ float As[64][36];
  __shared__ float Bs[32][128];
  const int tid = threadIdx.x;
  const int tx = tid & 15;
  const int ty = tid >> 4;
  const int row0 = blockIdx.x * 64;
  float acc[4][8];
#pragma unroll
  for (int i = 0; i < 4; ++i)
#pragma unroll
    for (int j = 0; j < 8; ++j) acc[i][j] = 0.f;

  const int ar = tid >> 3;
  const int ac = (tid & 7) * 4;
  const int br = tid >> 5;
  const int bc = (tid & 31) * 4;

  for (int k0 = 0; k0 < 256; k0 += 32) {
#pragma unroll
    for (int p = 0; p < 2; ++p) {
      int rr = ar + p * 32;
      int gr = row0 + rr; gr = gr < M ? gr : M - 1;
      float4 v = *reinterpret_cast<const float4*>(&A[(size_t)gr * 256 + k0 + ac]);
      As[rr][ac] = v.x; As[rr][ac + 1] = v.y; As[rr][ac + 2] = v.z; As[rr][ac + 3] = v.w;
    }
#pragma unroll
    for (int p = 0; p < 4; ++p) {
      int rr = br + p * 8;
      float4 v = *reinterpret_cast<const float4*>(&B[(size_t)(k0 + rr) * 128 + bc]);
      *reinterpret_cast<float4*>(&Bs[rr][bc]) = v;
    }
    __syncthreads();
#pragma unroll
    for (int kk = 0; kk < 32; ++kk) {
      float aa[4];
#pragma unroll
      for (int i = 0; i < 4; ++i) aa[i] = As[ty * 4 + i][kk];
      float4 b0 = *reinterpret_cast<const float4*>(&Bs[kk][tx * 4]);
      float4 b1 = *reinterpret_cast<const float4*>(&Bs[kk][64 + tx * 4]);
      float bb[8] = {b0.x, b0.y, b0.z, b0.w, b1.x, b1.y, b1.z, b1.w};
#pragma unroll
      for (int i = 0; i < 4; ++i)
#pragma unroll
        for (int j = 0; j < 8; ++j) acc[i][j] = fmaf(aa[i], bb[j], acc[i][j]);
    }
    __syncthreads();
  }
#pragma unroll
  for (int i = 0; i < 4; ++i) {
    int gr = row0 + ty * 4 + i;
    if (gr < M) {
      float4 v0 = make_float4(acc[i][0], acc[i][1], acc[i][2], acc[i][3]);
      float4 v1 = make_float4(acc[i][4], acc[i][5], acc[i][6], acc[i][7]);
      *reinterpret_cast<float4*>(&C[(size_t)gr * 128 + tx * 4]) = v0;
      *reinterpret_cast<float4*>(&C[(size_t)gr * 128 + 64 + tx * 4]) = v1;
    }
  }
}

__global__ __launch_bounds__(256) void gemm2_k(const float* __restrict__ A,
                                               const float* __restrict__ B,
                                               float* __restrict__ C, int M) {
  __shared__ float As[64][36];
  __shared__ float Bs[32][64];
  const int tid = threadIdx.x;
  const int tx = tid & 15;
  const int ty = tid >> 4;
  const int row0 = blockIdx.x * 64;
  float acc[4][4];
#pragma unroll
  for (int i = 0; i < 4; ++i)
#pragma unroll
    for (int j = 0; j < 4; ++j) acc[i][j] = 0.f;

  const int ar = tid >> 3;
  const int ac = (tid & 7) * 4;
  const int br = tid >> 4;
  const int bc = (tid & 15) * 4;

  for (int k0 = 0; k0 < 128; k0 += 32) {
#pragma unroll
    for (int p = 0; p < 2; ++p) {
      int rr = ar + p * 32;
      int gr = row0 + rr; gr = gr < M ? gr : M - 1;
      float4 v = *reinterpret_cast<const float4*>(&A[(size_t)gr * 128 + k0 + ac]);
      As[rr][ac]     = fmaxf(v.x, 0.f);
      As[rr][ac + 1] = fmaxf(v.y, 0.f);
      As[rr][ac + 2] = fmaxf(v.z, 0.f);
      As[rr][ac + 3] = fmaxf(v.w, 0.f);
    }
#pragma unroll
    for (int p = 0; p < 2; ++p) {
      int rr = br + p * 16;
      float4 v = *reinterpret_cast<const float4*>(&B[(size_t)(k0 + rr) * 64 + bc]);
      *reinterpret_cast<float4*>(&Bs[rr][bc]) = v;
    }
    __syncthreads();
#pragma unroll
    for (int kk = 0; kk < 32; ++kk) {
      float aa[4];
#pragma unroll
      for (int i = 0; i < 4; ++i) aa[i] = As[ty * 4 + i][kk];
      float4 b = *reinterpret_cast<const float4*>(&Bs[kk][tx * 4]);
      float bb[4] = {b.x, b.y, b.z, b.w};
#pragma unroll
      for (int i = 0; i < 4; ++i)
#pragma unroll
        for (int j = 0; j < 4; ++j) acc[i][j] = fmaf(aa[i], bb[j], acc[i][j]);
    }
    __syncthreads();
  }
#pragma unroll
  for (int i = 0; i < 4; ++i) {
    int gr = row0 + ty * 4 + i;
    if (gr < M) {
      float4 v = make_float4(acc[i][0], acc[i][1], acc[i][2], acc[i][3]);
      *reinterpret_cast<float4*>(&C[(size_t)gr * 64 + tx * 4]) = v;
    }
  }
}

// ================= per-node attention scores =================
__global__ __launch_bounds__(256) void att1_k(const float* __restrict__ h1,
                                              const float* __restrict__ asv,
                                              const float* __restrict__ adv,
                                              float* __restrict__ aS, float* __restrict__ aD,
                                              int N) {
  int w = (blockIdx.x * 256 + threadIdx.x) >> 6;
  int lane = threadIdx.x & 63;
  if (w >= N) return;
  float v0 = h1[(size_t)w * 128 + lane];
  float v1 = h1[(size_t)w * 128 + 64 + lane];
  float s0 = v0 * asv[lane], s1 = v1 * asv[64 + lane];
  float d0 = v0 * adv[lane], d1 = v1 * adv[64 + lane];
#pragma unroll
  for (int off = 32; off > 0; off >>= 1) {
    s0 += __shfl_xor(s0, off);
    s1 += __shfl_xor(s1, off);
    d0 += __shfl_xor(d0, off);
    d1 += __shfl_xor(d1, off);
  }
  if (lane == 0) {
    aS[w * 2] = s0; aS[w * 2 + 1] = s1;
    aD[w * 2] = d0; aD[w * 2 + 1] = d1;
  }
}

__global__ __launch_bounds__(256) void att2_k(const float* __restrict__ h2,
                                              const float* __restrict__ asv,
                                              const float* __restrict__ adv,
                                              float* __restrict__ aS, float* __restrict__ aD,
                                              int N) {
  int w = (blockIdx.x * 256 + threadIdx.x) >> 6;
  int lane = threadIdx.x & 63;
  if (w >= N) return;
  float v = h2[(size_t)w * 64 + lane];
  float s = v * asv[lane];
  float d = v * adv[lane];
#pragma unroll
  for (int off = 32; off > 0; off >>= 1) {
    s += __shfl_xor(s, off);
    d += __shfl_xor(d, off);
  }
  if (lane == 0) { aS[w] = s; aD[w] = d; }
}

// ================= CSR aggregation, layer 1: wave per (node, head) =================
__global__ __launch_bounds__(256) void csr_agg1_k(const int* __restrict__ srcs,
                                                  const int* __restrict__ off,
                                                  const float* __restrict__ aS,
                                                  const float* __restrict__ aD,
                                                  const float* __restrict__ h1,
                                                  const float* __restrict__ b1,
                                                  float* __restrict__ out1, int N) {
  int w = (blockIdx.x * 256 + threadIdx.x) >> 6;
  if (w >= 2 * N) return;
  int d = w >> 1, head = w & 1;
  int lane = threadIdx.x & 63;
  int s0 = off[d], s1 = off[d + 1];
  int deg = s1 - s0;
  float aDd = aD[2 * d + head];
  const float* hbase = h1 + (size_t)head * 64 + lane;
  float acc = b1[head * 64 + lane];

  if (deg <= 64) {
    // register-resident softmax: lane l owns edge (s0+l)
    int src = 0;
    float t = -1e30f;
    if (lane < deg) {
      src = srcs[s0 + lane];
      t = lrelu(aS[2 * src + head] + aDd);
    }
    float m = t;
#pragma unroll
    for (int o = 32; o > 0; o >>= 1) m = fmaxf(m, __shfl_xor(m, o));
    float wgt = (lane < deg) ? __expf(t - m) : 0.f;
    float sum = wgt;
#pragma unroll
    for (int o = 32; o > 0; o >>= 1) sum += __shfl_xor(sum, o);
    wgt *= (1.f / sum);

    int j = 0;
    for (; j + 4 <= deg; j += 4) {
      int i0 = __shfl(src, j), i1 = __shfl(src, j + 1),
          i2 = __shfl(src, j + 2), i3 = __shfl(src, j + 3);
      float a0 = __shfl(wgt, j), a1 = __shfl(wgt, j + 1),
            a2 = __shfl(wgt, j + 2), a3 = __shfl(wgt, j + 3);
      float v0 = hbase[(size_t)i0 * 128];
      float v1 = hbase[(size_t)i1 * 128];
      float v2 = hbase[(size_t)i2 * 128];
      float v3 = hbase[(size_t)i3 * 128];
      acc = fmaf(a0, v0, acc);
      acc = fmaf(a1, v1, acc);
      acc = fmaf(a2, v2, acc);
      acc = fmaf(a3, v3, acc);
    }
    for (; j < deg; ++j)
      acc = fmaf(__shfl(wgt, j), hbase[(size_t)__shfl(src, j) * 128], acc);
  } else {
    // general path (rare): 3 passes over the edge list
    float m = -1e30f;
    for (int i = s0 + lane; i < s1; i += 64)
      m = fmaxf(m, lrelu(aS[2 * srcs[i] + head] + aDd));
#pragma unroll
    for (int o = 32; o > 0; o >>= 1) m = fmaxf(m, __shfl_xor(m, o));
    float sum = 0.f;
    for (int i = s0 + lane; i < s1; i += 64)
      sum += __expf(lrelu(aS[2 * srcs[i] + head] + aDd) - m);
#pragma unroll
    for (int o = 32; o > 0; o >>= 1) sum += __shfl_xor(sum, o);
    float inv = 1.f / sum;
    for (int i = s0; i < s1; ++i) {
      int sj = srcs[i];
      float a = __expf(lrelu(aS[2 * sj + head] + aDd) - m) * inv;
      acc = fmaf(a, hbase[(size_t)sj * 128], acc);
    }
  }
  out1[(size_t)d * 128 + head * 64 + lane] = acc;
}

// ================= CSR aggregation, layer 2: wave per node =================
__global__ __launch_bounds__(256) void csr_agg2_k(const int* __restrict__ srcs,
                                                  const int* __restrict__ off,
                                                  const float* __restrict__ aS,
                                                  const float* __restrict__ aD,
                                                  const float* __restrict__ h2,
                                                  const float* __restrict__ b2,
                                                  float* __restrict__ out, int N) {
  int d = (blockIdx.x * 256 + threadIdx.x) >> 6;
  if (d >= N) return;
  int lane = threadIdx.x & 63;
  int s0 = off[d], s1 = off[d + 1];
  int deg = s1 - s0;
  float aDd = aD[d];
  const float* hbase = h2 + lane;
  float acc = b2[lane];

  if (deg <= 64) {
    int src = 0;
    float t = -1e30f;
    if (lane < deg) {
      src = srcs[s0 + lane];
      t = lrelu(aS[src] + aDd);
    }
    float m = t;
#pragma unroll
    for (int o = 32; o > 0; o >>= 1) m = fmaxf(m, __shfl_xor(m, o));
    float wgt = (lane < deg) ? __expf(t - m) : 0.f;
    float sum = wgt;
#pragma unroll
    for (int o = 32; o > 0; o >>= 1) sum += __shfl_xor(sum, o);
    wgt *= (1.f / sum);

    int j = 0;
    for (; j + 4 <= deg; j += 4) {
      int i0 = __shfl(src, j), i1 = __shfl(src, j + 1),
          i2 = __shfl(src, j + 2), i3 = __shfl(src, j + 3);
      float a0 = __shfl(wgt, j), a1 = __shfl(wgt, j + 1),
            a2 = __shfl(wgt, j + 2), a3 = __shfl(wgt, j + 3);
      float v0 = hbase[(size_t)i0 * 64];
      float v1 = hbase[(size_t)i1 * 64];
      float v2 = hbase[(size_t)i2 * 64];
      float v3 = hbase[(size_t)i3 * 64];
      acc = fmaf(a0, v0, acc);
      acc = fmaf(a1, v1, acc);
      acc = fmaf(a2, v2, acc);
      acc = fmaf(a3, v3, acc);
    }
    for (; j < deg; ++j)
      acc = fmaf(__shfl(wgt, j), hbase[(size_t)__shfl(src, j) * 64], acc);
  } else {
    float m = -1e30f;
    for (int i = s0 + lane; i < s1; i += 64)
      m = fmaxf(m, lrelu(aS[srcs[i]] + aDd));
#pragma unroll
    for (int o = 32; o > 0; o >>= 1) m = fmaxf(m, __shfl_xor(m, o));
    float sum = 0.f;
    for (int i = s0 + lane; i < s1; i += 64)
      sum += __expf(lrelu(aS[srcs[i]] + aDd) - m);
#pragma unroll
    for (int o = 32; o > 0; o >>= 1) sum += __shfl_xor(sum, o);
    float inv = 1.f / sum;
    for (int i = s0; i < s1; ++i) {
      int sj = srcs[i];
      float a = __expf(lrelu(aS[sj] + aDd) - m) * inv;
      acc = fmaf(a, hbase[(size_t)sj * 64], acc);
    }
  }
  out[(size_t)d * 64 + lane] = acc;
}

extern "C" void kernel_launch(void* const* d_in, const int* in_sizes, int n_in,
                              void* d_out, int out_size, void* d_ws, size_t ws_size,
                              hipStream_t stream) {
  const float* x   = (const float*)d_in[0];
  const int*   ei  = (const int*)d_in[1];
  const float* W1  = (const float*)d_in[2];
  const float* as1 = (const float*)d_in[3];
  const float* ad1 = (const float*)d_in[4];
  const float* b1  = (const float*)d_in[5];
  const float* W2  = (const float*)d_in[6];
  const float* as2 = (const float*)d_in[7];
  const float* ad2 = (const float*)d_in[8];
  const float* b2  = (const float*)d_in[9];
  float* out = (float*)d_out;

  const int N = in_sizes[0] / 256;
  const int E = in_sizes[1] / 2;
  const int NE = E + N;

  char* ws = (char*)d_ws;
  size_t woff = 0;
  auto take = [&](size_t bytes) -> char* {
    char* p = ws + woff;
    woff += (bytes + 255) & ~(size_t)255;
    return p;
  };
  float* h1   = (float*)take((size_t)N * 128 * 4);   // reused as h2
  float* out1 = (float*)take((size_t)N * 128 * 4);
  float* aS1  = (float*)take((size_t)N * 2 * 4);
  float* aD1  = (float*)take((size_t)N * 2 * 4);
  float* aS2  = (float*)take((size_t)N * 4);
  float* aD2  = (float*)take((size_t)N * 4);
  int*   deg  = (int*)take((size_t)N * 4);
  int*   part = (int*)take((size_t)N * 4);
  int*   offs = (int*)take((size_t)(N + 1) * 4);
  int*   bsum = (int*)take(256 * 4);
  int*   rank = (int*)take((size_t)NE * 4);
  int*   srcs = (int*)take((size_t)NE * 4);
  float* h2   = h1;

  const int egrid  = (NE + 255) / 256;
  const int wgrid1 = (2 * N + 3) / 4;     // wave per (node, head)
  const int wgrid2 = (N + 3) / 4;         // wave per node
  const int ngrid  = (N * 64 + 255) / 256;
  const int ggrid  = (N + 63) / 64;
  const int nb     = (N + 255) / 256;

  // ---- CSR build (shared by both layers) ----
  hipMemsetAsync(deg, 0, (size_t)N * 4, stream);
  hist_k<<<egrid, 256, 0, stream>>>(ei, deg, rank, E, NE);
  scan1_k<<<nb, 256, 0, stream>>>(deg, part, bsum, N);
  scan2_k<<<1, 256, 0, stream>>>(bsum, nb);
  scan3_k<<<nb, 256, 0, stream>>>(part, bsum, offs, N, NE);
  scatter_k<<<egrid, 256, 0, stream>>>(ei, offs, rank, srcs, E, NE);

  // ---- layer 1 ----
  gemm1_k<<<ggrid, 256, 0, stream>>>(x, W1, h1, N);
  att1_k<<<ngrid, 256, 0, stream>>>(h1, as1, ad1, aS1, aD1, N);
  csr_agg1_k<<<wgrid1, 256, 0, stream>>>(srcs, offs, aS1, aD1, h1, b1, out1, N);

  // ---- layer 2 ----
  gemm2_k<<<ggrid, 256, 0, stream>>>(out1, W2, h2, N);
  att2_k<<<ngrid, 256, 0, stream>>>(h2, as2, ad2, aS2, aD2, N);
  csr_agg2_k<<<wgrid2, 256, 0, stream>>>(srcs, offs, aS2, aD2, h2, b2, out, N);
}

// Round 4
// 181.454 us; speedup vs baseline: 4.8419x; 1.4412x over previous
//
#include <hip/hip_runtime.h>
#include <math.h>

#define NEG_SLOPE 0.2f

typedef unsigned short u16;
typedef unsigned int u32;
typedef _Float16 f16;
typedef __attribute__((ext_vector_type(8))) _Float16 f16x8;
typedef __attribute__((ext_vector_type(4))) float f32x4;

__device__ __forceinline__ float lrelu(float x) { return x > 0.f ? x : NEG_SLOPE * x; }
__device__ __forceinline__ u16 f2h(float f) { f16 h = (f16)f; return __builtin_bit_cast(u16, h); }
__device__ __forceinline__ float h2f(u16 u) { return (float)__builtin_bit_cast(f16, u); }
__device__ __forceinline__ float2 hp2f(u32 v) {
  union { u32 u; f16 h[2]; } c; c.u = v;
  return make_float2((float)c.h[0], (float)c.h[1]);
}
__device__ __forceinline__ u32 pk2h(float a, float b) {
  return (u32)f2h(a) | ((u32)f2h(b) << 16);
}

// ================= prep: transpose + f16-convert weights =================
__global__ void prep_k(const float* __restrict__ W1, const float* __restrict__ W2,
                       u16* __restrict__ W1t, u16* __restrict__ W2t) {
  int i = blockIdx.x * 256 + threadIdx.x;
  if (i < 128 * 256) { int n = i >> 8, k = i & 255; W1t[i] = f2h(W1[k * 128 + n]); }
  if (i < 64 * 128)  { int n = i >> 7, k = i & 127; W2t[i] = f2h(W2[k * 64 + n]); }
}

// ================= CSR build =================
__global__ void hist_k(const int* __restrict__ ei, int* __restrict__ deg,
                       int* __restrict__ rank, int E, int NE) {
  int e = blockIdx.x * blockDim.x + threadIdx.x;
  if (e >= NE) return;
  int dst = (e < E) ? ei[E + e] : e - E;
  rank[e] = atomicAdd(&deg[dst], 1);
}

__global__ void scan1_k(const int* __restrict__ deg, int* __restrict__ part,
                        int* __restrict__ bsum, int N) {
  __shared__ int tmp[256];
  int i = blockIdx.x * 256 + threadIdx.x;
  int v = (i < N) ? deg[i] : 0;
  tmp[threadIdx.x] = v;
  __syncthreads();
#pragma unroll
  for (int off = 1; off < 256; off <<= 1) {
    int t = (threadIdx.x >= off) ? tmp[threadIdx.x - off] : 0;
    __syncthreads();
    tmp[threadIdx.x] += t;
    __syncthreads();
  }
  if (i < N) part[i] = tmp[threadIdx.x] - v;
  if (threadIdx.x == 255) bsum[blockIdx.x] = tmp[255];
}

__global__ void scan2_k(int* __restrict__ bsum, int nb) {
  __shared__ int tmp[256];
  int v = (threadIdx.x < nb) ? bsum[threadIdx.x] : 0;
  tmp[threadIdx.x] = v;
  __syncthreads();
#pragma unroll
  for (int off = 1; off < 256; off <<= 1) {
    int t = (threadIdx.x >= off) ? tmp[threadIdx.x - off] : 0;
    __syncthreads();
    tmp[threadIdx.x] += t;
    __syncthreads();
  }
  if (threadIdx.x < nb) bsum[threadIdx.x] = tmp[threadIdx.x] - v;
}

__global__ void scan3_k(const int* __restrict__ part, const int* __restrict__ bsum,
                        int* __restrict__ off, int N, int NE) {
  int i = blockIdx.x * 256 + threadIdx.x;
  if (i < N) off[i] = part[i] + bsum[blockIdx.x];
  if (i == 0) off[N] = NE;
}

__global__ void scatter_k(const int* __restrict__ ei, const int* __restrict__ off,
                          const int* __restrict__ rank, int* __restrict__ srcs,
                          int E, int NE) {
  int e = blockIdx.x * blockDim.x + threadIdx.x;
  if (e >= NE) return;
  int src, dst;
  if (e < E) { src = ei[e]; dst = ei[E + e]; } else { src = e - E; dst = src; }
  srcs[off[dst] + rank[e]] = src;
}

// ================= GEMM1 (MFMA f16): h1[M][128] = x[M][256] @ W1, f16 out =================
__global__ __launch_bounds__(256) void gemm1_mfma_k(const float* __restrict__ A,
                                                    const u16* __restrict__ Bt,  // [128][256]
                                                    u16* __restrict__ C, int M) {
  __shared__ u16 Ah[64][40];
  __shared__ u16 Bh[128][40];
  const int tid = threadIdx.x;
  const int lane = tid & 63;
  const int wid = tid >> 6;
  const int wm = wid >> 1, wn = wid & 1;
  const int row0 = blockIdx.x * 64;
  const int l15 = lane & 15;
  const int k8 = (lane >> 4) * 8;

  f32x4 acc[2][4];
#pragma unroll
  for (int i = 0; i < 2; ++i)
#pragma unroll
    for (int j = 0; j < 4; ++j) acc[i][j] = (f32x4){0.f, 0.f, 0.f, 0.f};

  const int ar = tid >> 3;        // 0..31
  const int ac = (tid & 7) * 4;   // 0,4,..28
  const int bn = tid >> 1;        // 0..127
  const int bk = (tid & 1) * 16;  // 0 or 16

  for (int k0 = 0; k0 < 256; k0 += 32) {
#pragma unroll
    for (int p = 0; p < 2; ++p) {
      int rr = ar + p * 32;
      int gr = row0 + rr; gr = gr < M ? gr : M - 1;
      float4 v = *reinterpret_cast<const float4*>(&A[(size_t)gr * 256 + k0 + ac]);
      uint2 w; w.x = pk2h(v.x, v.y); w.y = pk2h(v.z, v.w);
      *reinterpret_cast<uint2*>(&Ah[rr][ac]) = w;
    }
    {
      int4 v = *reinterpret_cast<const int4*>(&Bt[(size_t)bn * 256 + k0 + bk]);
      *reinterpret_cast<int4*>(&Bh[bn][bk]) = v;
      int4 v2 = *reinterpret_cast<const int4*>(&Bt[(size_t)bn * 256 + k0 + bk + 8]);
      *reinterpret_cast<int4*>(&Bh[bn][bk + 8]) = v2;
    }
    __syncthreads();
    f16x8 af[2], bf[4];
#pragma unroll
    for (int mf = 0; mf < 2; ++mf)
      af[mf] = *reinterpret_cast<const f16x8*>(&Ah[wm * 32 + mf * 16 + l15][k8]);
#pragma unroll
    for (int nf = 0; nf < 4; ++nf)
      bf[nf] = *reinterpret_cast<const f16x8*>(&Bh[wn * 64 + nf * 16 + l15][k8]);
#pragma unroll
    for (int mf = 0; mf < 2; ++mf)
#pragma unroll
      for (int nf = 0; nf < 4; ++nf)
        acc[mf][nf] = __builtin_amdgcn_mfma_f32_16x16x32_f16(af[mf], bf[nf], acc[mf][nf], 0, 0, 0);
    __syncthreads();
  }
#pragma unroll
  for (int mf = 0; mf < 2; ++mf)
#pragma unroll
    for (int r = 0; r < 4; ++r) {
      int row = row0 + wm * 32 + mf * 16 + (lane >> 4) * 4 + r;
      if (row < M) {
#pragma unroll
        for (int nf = 0; nf < 4; ++nf)
          C[(size_t)row * 128 + wn * 64 + nf * 16 + l15] = f2h(acc[mf][nf][r]);
      }
    }
}

// ================= GEMM2 (MFMA f16): h2[M][64] = relu(out1[M][128]) @ W2, f16 out =========
__global__ __launch_bounds__(256) void gemm2_mfma_k(const float* __restrict__ A,
                                                    const u16* __restrict__ Bt,  // [64][128]
                                                    u16* __restrict__ C, int M) {
  __shared__ u16 Ah[64][40];
  __shared__ u16 Bh[64][40];
  const int tid = threadIdx.x;
  const int lane = tid & 63;
  const int wid = tid >> 6;
  const int wm = wid >> 1, wn = wid & 1;
  const int row0 = blockIdx.x * 64;
  const int l15 = lane & 15;
  const int k8 = (lane >> 4) * 8;

  f32x4 acc[2][2];
#pragma unroll
  for (int i = 0; i < 2; ++i)
#pragma unroll
    for (int j = 0; j < 2; ++j) acc[i][j] = (f32x4){0.f, 0.f, 0.f, 0.f};

  const int ar = tid >> 3;
  const int ac = (tid & 7) * 4;
  const int bn = tid >> 1;        // 0..127 (only <64 used)
  const int bk = (tid & 1) * 16;

  for (int k0 = 0; k0 < 128; k0 += 32) {
#pragma unroll
    for (int p = 0; p < 2; ++p) {
      int rr = ar + p * 32;
      int gr = row0 + rr; gr = gr < M ? gr : M - 1;
      float4 v = *reinterpret_cast<const float4*>(&A[(size_t)gr * 128 + k0 + ac]);
      uint2 w;
      w.x = pk2h(fmaxf(v.x, 0.f), fmaxf(v.y, 0.f));
      w.y = pk2h(fmaxf(v.z, 0.f), fmaxf(v.w, 0.f));
      *reinterpret_cast<uint2*>(&Ah[rr][ac]) = w;
    }
    if (bn < 64) {
      int4 v = *reinterpret_cast<const int4*>(&Bt[(size_t)bn * 128 + k0 + bk]);
      *reinterpret_cast<int4*>(&Bh[bn][bk]) = v;
      int4 v2 = *reinterpret_cast<const int4*>(&Bt[(size_t)bn * 128 + k0 + bk + 8]);
      *reinterpret_cast<int4*>(&Bh[bn][bk + 8]) = v2;
    }
    __syncthreads();
    f16x8 af[2], bf[2];
#pragma unroll
    for (int mf = 0; mf < 2; ++mf)
      af[mf] = *reinterpret_cast<const f16x8*>(&Ah[wm * 32 + mf * 16 + l15][k8]);
#pragma unroll
    for (int nf = 0; nf < 2; ++nf)
      bf[nf] = *reinterpret_cast<const f16x8*>(&Bh[wn * 32 + nf * 16 + l15][k8]);
#pragma unroll
    for (int mf = 0; mf < 2; ++mf)
#pragma unroll
      for (int nf = 0; nf < 2; ++nf)
        acc[mf][nf] = __builtin_amdgcn_mfma_f32_16x16x32_f16(af[mf], bf[nf], acc[mf][nf], 0, 0, 0);
    __syncthreads();
  }
#pragma unroll
  for (int mf = 0; mf < 2; ++mf)
#pragma unroll
    for (int r = 0; r < 4; ++r) {
      int row = row0 + wm * 32 + mf * 16 + (lane >> 4) * 4 + r;
      if (row < M) {
#pragma unroll
        for (int nf = 0; nf < 2; ++nf)
          C[(size_t)row * 64 + wn * 32 + nf * 16 + l15] = f2h(acc[mf][nf][r]);
      }
    }
}

// ================= per-node attention scores (f16 h) =================
__global__ __launch_bounds__(256) void att1_k(const u16* __restrict__ h1,
                                              const float* __restrict__ asv,
                                              const float* __restrict__ adv,
                                              float* __restrict__ aS, float* __restrict__ aD,
                                              int N) {
  int w = (blockIdx.x * 256 + threadIdx.x) >> 6;
  int lane = threadIdx.x & 63;
  if (w >= N) return;
  u32 v = reinterpret_cast<const u32*>(h1)[(size_t)w * 64 + lane];
  float2 f = hp2f(v);
  float s = f.x * asv[2 * lane] + f.y * asv[2 * lane + 1];
  float d = f.x * adv[2 * lane] + f.y * adv[2 * lane + 1];
#pragma unroll
  for (int o = 16; o > 0; o >>= 1) {  // reduce within 32-lane halves (one head each)
    s += __shfl_xor(s, o);
    d += __shfl_xor(d, o);
  }
  if (lane == 0)  { aS[2 * w] = s;     aD[2 * w] = d; }
  if (lane == 32) { aS[2 * w + 1] = s; aD[2 * w + 1] = d; }
}

__global__ __launch_bounds__(256) void att2_k(const u16* __restrict__ h2,
                                              const float* __restrict__ asv,
                                              const float* __restrict__ adv,
                                              float* __restrict__ aS, float* __restrict__ aD,
                                              int N) {
  int w = (blockIdx.x * 256 + threadIdx.x) >> 6;
  int lane = threadIdx.x & 63;
  if (w >= N) return;
  float f = h2f(h2[(size_t)w * 64 + lane]);
  float s = f * asv[lane];
  float d = f * adv[lane];
#pragma unroll
  for (int o = 32; o > 0; o >>= 1) {
    s += __shfl_xor(s, o);
    d += __shfl_xor(d, o);
  }
  if (lane == 0) { aS[w] = s; aD[w] = d; }
}

// ================= agg layer 1: wave per node, both heads, f16 gather =================
__global__ __launch_bounds__(256) void csr_agg1_k(const int* __restrict__ srcs,
                                                  const int* __restrict__ off,
                                                  const float* __restrict__ aS,
                                                  const float* __restrict__ aD,
                                                  const u16* __restrict__ h1,
                                                  const float* __restrict__ b1,
                                                  float* __restrict__ out1, int N) {
  int d = (blockIdx.x * 256 + threadIdx.x) >> 6;
  if (d >= N) return;
  int lane = threadIdx.x & 63;
  int s0 = off[d], s1 = off[d + 1];
  int deg = s1 - s0;
  float aD0 = aD[2 * d], aD1 = aD[2 * d + 1];
  const u32* h1u = reinterpret_cast<const u32*>(h1);
  float acc0 = b1[2 * lane], acc1 = b1[2 * lane + 1];

  if (deg <= 64) {
    int src = 0;
    float t0 = -1e30f, t1 = -1e30f;
    if (lane < deg) {
      src = srcs[s0 + lane];
      float2 sv = *reinterpret_cast<const float2*>(&aS[2 * src]);
      t0 = lrelu(sv.x + aD0); t1 = lrelu(sv.y + aD1);
    }
    float m0 = t0, m1 = t1;
#pragma unroll
    for (int o = 32; o > 0; o >>= 1) {
      m0 = fmaxf(m0, __shfl_xor(m0, o));
      m1 = fmaxf(m1, __shfl_xor(m1, o));
    }
    float w0 = (lane < deg) ? __expf(t0 - m0) : 0.f;
    float w1 = (lane < deg) ? __expf(t1 - m1) : 0.f;
    float sum0 = w0, sum1 = w1;
#pragma unroll
    for (int o = 32; o > 0; o >>= 1) {
      sum0 += __shfl_xor(sum0, o);
      sum1 += __shfl_xor(sum1, o);
    }
    w0 *= (1.f / sum0); w1 *= (1.f / sum1);

    int j = 0;
    for (; j + 4 <= deg; j += 4) {
      int s_[4]; float a_[4]; u32 v_[4];
#pragma unroll
      for (int q = 0; q < 4; ++q) {
        s_[q] = __shfl(src, j + q);
        float a0 = __shfl(w0, j + q), a1 = __shfl(w1, j + q);
        a_[q] = (lane < 32) ? a0 : a1;
      }
#pragma unroll
      for (int q = 0; q < 4; ++q) v_[q] = h1u[(size_t)s_[q] * 64 + lane];
#pragma unroll
      for (int q = 0; q < 4; ++q) {
        float2 f = hp2f(v_[q]);
        acc0 = fmaf(a_[q], f.x, acc0);
        acc1 = fmaf(a_[q], f.y, acc1);
      }
    }
    for (; j < deg; ++j) {
      int sj = __shfl(src, j);
      float a0 = __shfl(w0, j), a1 = __shfl(w1, j);
      float a = (lane < 32) ? a0 : a1;
      float2 f = hp2f(h1u[(size_t)sj * 64 + lane]);
      acc0 = fmaf(a, f.x, acc0);
      acc1 = fmaf(a, f.y, acc1);
    }
  } else {
    float m0 = -1e30f, m1 = -1e30f;
    for (int i = s0 + lane; i < s1; i += 64) {
      int sj = srcs[i];
      float2 sv = *reinterpret_cast<const float2*>(&aS[2 * sj]);
      m0 = fmaxf(m0, lrelu(sv.x + aD0));
      m1 = fmaxf(m1, lrelu(sv.y + aD1));
    }
#pragma unroll
    for (int o = 32; o > 0; o >>= 1) {
      m0 = fmaxf(m0, __shfl_xor(m0, o));
      m1 = fmaxf(m1, __shfl_xor(m1, o));
    }
    float sum0 = 0.f, sum1 = 0.f;
    for (int i = s0 + lane; i < s1; i += 64) {
      int sj = srcs[i];
      float2 sv = *reinterpret_cast<const float2*>(&aS[2 * sj]);
      sum0 += __expf(lrelu(sv.x + aD0) - m0);
      sum1 += __expf(lrelu(sv.y + aD1) - m1);
    }
#pragma unroll
    for (int o = 32; o > 0; o >>= 1) {
      sum0 += __shfl_xor(sum0, o);
      sum1 += __shfl_xor(sum1, o);
    }
    float inv0 = 1.f / sum0, inv1 = 1.f / sum1;
    int head = lane >> 5;
    float mh = head ? m1 : m0, invh = head ? inv1 : inv0, aDh = head ? aD1 : aD0;
    for (int i = s0; i < s1; ++i) {
      int sj = srcs[i];
      float t = lrelu(aS[2 * sj + head] + aDh);
      float a = __expf(t - mh) * invh;
      float2 f = hp2f(h1u[(size_t)sj * 64 + lane]);
      acc0 = fmaf(a, f.x, acc0);
      acc1 = fmaf(a, f.y, acc1);
    }
  }
  *reinterpret_cast<float2*>(&out1[(size_t)d * 128 + 2 * lane]) = make_float2(acc0, acc1);
}

// ================= agg layer 2: wave per node, 2 edges/round across half-waves =========
__global__ __launch_bounds__(256) void csr_agg2_k(const int* __restrict__ srcs,
                                                  const int* __restrict__ off,
                                                  const float* __restrict__ aS,
                                                  const float* __restrict__ aD,
                                                  const u16* __restrict__ h2,
                                                  const float* __restrict__ b2,
                                                  float* __restrict__ out, int N) {
  int d = (blockIdx.x * 256 + threadIdx.x) >> 6;
  if (d >= N) return;
  int lane = threadIdx.x & 63;
  int s0 = off[d], s1 = off[d + 1];
  int deg = s1 - s0;
  float aDd = aD[d];
  const u32* h2u = reinterpret_cast<const u32*>(h2);
  int half = lane >> 5;
  int l31 = lane & 31;
  float acc0 = 0.f, acc1 = 0.f;

  if (deg <= 64) {
    int src = 0;
    float t = -1e30f;
    if (lane < deg) {
      src = srcs[s0 + lane];
      t = lrelu(aS[src] + aDd);
    }
    float m = t;
#pragma unroll
    for (int o = 32; o > 0; o >>= 1) m = fmaxf(m, __shfl_xor(m, o));
    float w = (lane < deg) ? __expf(t - m) : 0.f;
    float sum = w;
#pragma unroll
    for (int o = 32; o > 0; o >>= 1) sum += __shfl_xor(sum, o);
    w *= (1.f / sum);

    int j = 0;
    for (; j + 4 <= deg; j += 4) {
      int e0 = j + half, e1 = j + 2 + half;
      int se0 = __shfl(src, e0), se1 = __shfl(src, e1);
      float a0 = __shfl(w, e0), a1 = __shfl(w, e1);
      u32 v0 = h2u[(size_t)se0 * 32 + l31];
      u32 v1 = h2u[(size_t)se1 * 32 + l31];
      float2 f0 = hp2f(v0), f1 = hp2f(v1);
      acc0 = fmaf(a0, f0.x, acc0); acc1 = fmaf(a0, f0.y, acc1);
      acc0 = fmaf(a1, f1.x, acc0); acc1 = fmaf(a1, f1.y, acc1);
    }
    for (; j < deg; j += 2) {
      int e = j + half;
      int ec = e < deg ? e : 0;
      int se = __shfl(src, ec);
      float a = __shfl(w, ec);
      if (e >= deg) a = 0.f;
      float2 f = hp2f(h2u[(size_t)se * 32 + l31]);
      acc0 = fmaf(a, f.x, acc0); acc1 = fmaf(a, f.y, acc1);
    }
  } else {
    float m = -1e30f;
    for (int i = s0 + lane; i < s1; i += 64)
      m = fmaxf(m, lrelu(aS[srcs[i]] + aDd));
#pragma unroll
    for (int o = 32; o > 0; o >>= 1) m = fmaxf(m, __shfl_xor(m, o));
    float sum = 0.f;
    for (int i = s0 + lane; i < s1; i += 64)
      sum += __expf(lrelu(aS[srcs[i]] + aDd) - m);
#pragma unroll
    for (int o = 32; o > 0; o >>= 1) sum += __shfl_xor(sum, o);
    float inv = 1.f / sum;
    for (int i = s0; i < s1; ++i) {
      int sj = srcs[i];
      float a = __expf(lrelu(aS[sj] + aDd) - m) * inv;
      if (lane < 32) {
        float2 f = hp2f(h2u[(size_t)sj * 32 + l31]);
        acc0 = fmaf(a, f.x, acc0); acc1 = fmaf(a, f.y, acc1);
      }
    }
  }
  acc0 += __shfl_xor(acc0, 32);
  acc1 += __shfl_xor(acc1, 32);
  if (lane < 32)
    *reinterpret_cast<float2*>(&out[(size_t)d * 64 + 2 * l31]) =
        make_float2(b2[2 * l31] + acc0, b2[2 * l31 + 1] + acc1);
}

extern "C" void kernel_launch(void* const* d_in, const int* in_sizes, int n_in,
                              void* d_out, int out_size, void* d_ws, size_t ws_size,
                              hipStream_t stream) {
  const float* x   = (const float*)d_in[0];
  const int*   ei  = (const int*)d_in[1];
  const float* W1  = (const float*)d_in[2];
  const float* as1 = (const float*)d_in[3];
  const float* ad1 = (const float*)d_in[4];
  const float* b1  = (const float*)d_in[5];
  const float* W2  = (const float*)d_in[6];
  const float* as2 = (const float*)d_in[7];
  const float* ad2 = (const float*)d_in[8];
  const float* b2  = (const float*)d_in[9];
  float* out = (float*)d_out;

  const int N = in_sizes[0] / 256;
  const int E = in_sizes[1] / 2;
  const int NE = E + N;

  char* ws = (char*)d_ws;
  size_t woff = 0;
  auto take = [&](size_t bytes) -> char* {
    char* p = ws + woff;
    woff += (bytes + 255) & ~(size_t)255;
    return p;
  };
  u16*   h1   = (u16*)take((size_t)N * 128 * 2);   // f16; reused as h2 after agg1
  float* out1 = (float*)take((size_t)N * 128 * 4);
  float* aS1  = (float*)take((size_t)N * 2 * 4);
  float* aD1  = (float*)take((size_t)N * 2 * 4);
  float* aS2  = (float*)take((size_t)N * 4);
  float* aD2  = (float*)take((size_t)N * 4);
  int*   deg  = (int*)take((size_t)N * 4);
  int*   part = (int*)take((size_t)N * 4);
  int*   offs = (int*)take((size_t)(N + 1) * 4);
  int*   bsum = (int*)take(256 * 4);
  int*   rank = (int*)take((size_t)NE * 4);
  int*   srcs = (int*)take((size_t)NE * 4);
  u16*   W1t  = (u16*)take((size_t)128 * 256 * 2);
  u16*   W2t  = (u16*)take((size_t)64 * 128 * 2);
  u16*   h2   = h1;  // alias: h1 dead after csr_agg1_k

  const int egrid = (NE + 255) / 256;
  const int wgrid = (N + 3) / 4;          // wave-per-node kernels
  const int ngrid = (N * 64 + 255) / 256;
  const int ggrid = (N + 63) / 64;
  const int nb    = (N + 255) / 256;

  // ---- prep + CSR build ----
  prep_k<<<128, 256, 0, stream>>>(W1, W2, W1t, W2t);
  hipMemsetAsync(deg, 0, (size_t)N * 4, stream);
  hist_k<<<egrid, 256, 0, stream>>>(ei, deg, rank, E, NE);
  scan1_k<<<nb, 256, 0, stream>>>(deg, part, bsum, N);
  scan2_k<<<1, 256, 0, stream>>>(bsum, nb);
  scan3_k<<<nb, 256, 0, stream>>>(part, bsum, offs, N, NE);
  scatter_k<<<egrid, 256, 0, stream>>>(ei, offs, rank, srcs, E, NE);

  // ---- layer 1 ----
  gemm1_mfma_k<<<ggrid, 256, 0, stream>>>(x, W1t, h1, N);
  att1_k<<<ngrid, 256, 0, stream>>>(h1, as1, ad1, aS1, aD1, N);
  csr_agg1_k<<<wgrid, 256, 0, stream>>>(srcs, offs, aS1, aD1, h1, b1, out1, N);

  // ---- layer 2 ----
  gemm2_mfma_k<<<ggrid, 256, 0, stream>>>(out1, W2t, h2, N);
  att2_k<<<ngrid, 256, 0, stream>>>(h2, as2, ad2, aS2, aD2, N);
  csr_agg2_k<<<wgrid, 256, 0, stream>>>(srcs, offs, aS2, aD2, h2, b2, out, N);
}